// Round 8
// baseline (54.160 us; speedup 1.0000x reference)
//
#include <hip/hip_runtime.h>
#include <hip/hip_bf16.h>

#define NEG_BIG -1000000.0f

typedef __attribute__((ext_vector_type(8))) short short8;
typedef __attribute__((ext_vector_type(4))) short short4v;
typedef __attribute__((ext_vector_type(4))) float floatx4;

#if __has_builtin(__builtin_amdgcn_exp2f)
#define EXP2F(x) __builtin_amdgcn_exp2f(x)
#else
#define EXP2F(x) exp2f(x)
#endif

// K=16 bf16 MFMA (PV step): A[row=lane&15][k=4*(lane>>4)+j]
#if __has_builtin(__builtin_amdgcn_mfma_f32_16x16x16bf16_1k)
#define MFMA16(a, b, c) __builtin_amdgcn_mfma_f32_16x16x16bf16_1k(a, b, c, 0, 0, 0)
#else
static __device__ __forceinline__ floatx4 MFMA16_fn(short4v a, short4v b, floatx4 c) {
    floatx4 d;
    asm("v_mfma_f32_16x16x16_bf16 %0, %1, %2, %3\n\ts_nop 4"
        : "=v"(d) : "v"(a), "v"(b), "v"(c));
    return d;
}
#define MFMA16(a, b, c) MFMA16_fn(a, b, c)
#endif

// xor16 + xor32 wave reduction on the VALU (permlane swaps) instead of
// ds_bpermute (LDS pipe, ~100cyc serial hops).
#if __has_builtin(__builtin_amdgcn_permlane16_swap) && __has_builtin(__builtin_amdgcn_permlane32_swap)
static __device__ __forceinline__ float redmax16_32(float x) {
    auto a = __builtin_amdgcn_permlane16_swap(__float_as_int(x), __float_as_int(x), false, false);
    x = fmaxf(__int_as_float(a[0]), __int_as_float(a[1]));
    auto b = __builtin_amdgcn_permlane32_swap(__float_as_int(x), __float_as_int(x), false, false);
    return fmaxf(__int_as_float(b[0]), __int_as_float(b[1]));
}
static __device__ __forceinline__ float redsum16_32(float x) {
    auto a = __builtin_amdgcn_permlane16_swap(__float_as_int(x), __float_as_int(x), false, false);
    x = __int_as_float(a[0]) + __int_as_float(a[1]);
    auto b = __builtin_amdgcn_permlane32_swap(__float_as_int(x), __float_as_int(x), false, false);
    return __int_as_float(b[0]) + __int_as_float(b[1]);
}
#else
static __device__ __forceinline__ float redmax16_32(float x) {
    x = fmaxf(x, __shfl_xor(x, 16));
    return fmaxf(x, __shfl_xor(x, 32));
}
static __device__ __forceinline__ float redsum16_32(float x) {
    x += __shfl_xor(x, 16);
    return x + __shfl_xor(x, 32);
}
#endif

static __device__ __forceinline__ unsigned short bf16u(float f) {
    union { __hip_bfloat16 h; unsigned short u; } c;
    c.h = __float2bfloat16(f);
    return c.u;
}

static __device__ __forceinline__ short8 pack8(float4 a, float4 b) {
    union { short8 s; __hip_bfloat162 h[4]; } u;
    u.h[0] = __float22bfloat162_rn(make_float2(a.x, a.y));
    u.h[1] = __float22bfloat162_rn(make_float2(a.z, a.w));
    u.h[2] = __float22bfloat162_rn(make_float2(b.x, b.y));
    u.h[3] = __float22bfloat162_rn(make_float2(b.z, b.w));
    return u.s;
}

// PERSISTENT kernel: 768 blocks (= 3/CU, co-resident). Each block pulls
// (b, qc) sites from a global atomic queue (ctr in d_ws, memset to 0 on the
// stream each launch) -> no drain phase, tail bounded by one 16-tile site.
// Per site: 4 waves, 64 q-rows (wave owns one 16-row tile), KV tile 64,
// double-buffered 32 KB LDS, one barrier per tile, swapped QK^T (lane-local
// softmax, in-register P), permlane reductions, deferred rescale (THR=11,
// exp2 domain). The site-grab barrier doubles as the LDS-reuse guard.
__global__ __launch_bounds__(256, 3)
void attn_fwd(const float* __restrict__ Q, const float* __restrict__ K,
              const float* __restrict__ V, const int* __restrict__ vlen,
              float* __restrict__ out, int* __restrict__ ctr)
{
    // K_lds: elem (row,col) at row*64 + (col ^ ((row&7)*8))
    __shared__ __attribute__((aligned(16))) unsigned short K_lds[2][4096];
    // VT_lds: elem (dv,k) at dv*64 + (k ^ (((dv&7) ^ (dv>>3)) * 8))
    __shared__ __attribute__((aligned(16))) unsigned short VT_lds[2][4096];
    __shared__ int s_site;

    const int tid = threadIdx.x;
    const int l   = tid & 63;
    const int w   = tid >> 6;
    const int lr  = l & 15;
    const int lg  = l >> 4;

    // staging geometry: wave w stages tile rows [w*16, w*16+16)
    const int row   = w * 16 + (l >> 2);  // 0..63
    const int cbase = (l & 3) * 16;       // col quarter (floats)

    const float qscale = 0.18033688011112042f;  // log2(e)/sqrt(64)

    for (;;) {
        if (tid == 0) s_site = atomicAdd(ctr, 1);
        __syncthreads();                   // broadcast + LDS-reuse guard
        const int site = s_site;
        if (site >= 1024) return;          // block-uniform
        const int b  = site >> 4;
        const int qc = site & 15;

        const int valid = vlen[b];
        const int kmax  = (valid == 0) ? 1024 : valid;  // all-masked -> uniform
        const int ntile = (kmax + 63) >> 6;

        const float* Qb = Q + (size_t)b * 65536;
        const float* Kb = K + (size_t)b * 65536;
        const float* Vb = V + (size_t)b * 65536;

        float4 kra[4], vra[4];

#define LOAD_K(T) do {                                                      \
    const float* pk = Kb + (size_t)((T)*64 + row) * 64 + cbase;             \
    kra[0] = *(const float4*)pk;       kra[1] = *(const float4*)(pk + 4);   \
    kra[2] = *(const float4*)(pk + 8); kra[3] = *(const float4*)(pk + 12);  \
    } while (0)

#define LOAD_V(T) do {                                                      \
    const float* pv = Vb + (size_t)((T)*64 + row) * 64 + cbase;             \
    vra[0] = *(const float4*)pv;       vra[1] = *(const float4*)(pv + 4);   \
    vra[2] = *(const float4*)(pv + 8); vra[3] = *(const float4*)(pv + 12);  \
    } while (0)

#define WRITE_K(B) do {                                                     \
    const int _fk = (row & 7) * 8;                                          \
    *(short8*)&K_lds[B][row*64 + (cbase ^ _fk)]       = pack8(kra[0], kra[1]); \
    *(short8*)&K_lds[B][row*64 + ((cbase + 8) ^ _fk)] = pack8(kra[2], kra[3]); \
    } while (0)

#define WRITE_V(B) do {                                                     \
    _Pragma("unroll")                                                       \
    for (int j = 0; j < 16; ++j) {                                          \
        const int dv = cbase + j;                                           \
        const int fv = ((dv & 7) ^ (dv >> 3)) * 8;                          \
        VT_lds[B][dv*64 + (row ^ fv)] = bf16u(((const float*)&vra[j>>2])[j&3]); \
    } } while (0)

        LOAD_K(0);
        LOAD_V(0);

        // Q fragments (B-operand of swapped QK^T) — loads overlap K/V latency
        short8 qf[2];
#pragma unroll
        for (int c = 0; c < 2; ++c) {
            const float* p = Qb + (size_t)(qc*64 + w*16 + lr) * 64 + c*32 + lg*8;
            float4 a = *(const float4*)p, bb = *(const float4*)(p + 4);
            a.x *= qscale; a.y *= qscale; a.z *= qscale; a.w *= qscale;
            bb.x *= qscale; bb.y *= qscale; bb.z *= qscale; bb.w *= qscale;
            qf[c] = pack8(a, bb);
        }

        floatx4 o[4];
#pragma unroll
        for (int n = 0; n < 4; ++n) o[n] = (floatx4){0.f, 0.f, 0.f, 0.f};
        float m = -INFINITY, lsum = 0.f;   // scalar state for q-row lr

        WRITE_K(0);
        WRITE_V(0);
        __syncthreads();

        for (int t = 0; t < ntile; ++t) {
            const int cur = t & 1;
            const int nxt = cur ^ 1;
            const int k0  = t * 64;
            const bool pf = (t + 1 < ntile);

            if (pf) { LOAD_K(t + 1); LOAD_V(t + 1); }  // max load->use distance

            // ---- swapped QK^T: sa[n][r] = S[k=k0+n*16+lg*4+r][q=lr] ----
            floatx4 sa[4];
            __builtin_amdgcn_s_setprio(1);
#pragma unroll
            for (int n = 0; n < 4; ++n) {
                const int kr = n*16 + lr;
                const int fk = (lr & 7) * 8;
                const short8 kf0 = *(const short8*)&K_lds[cur][kr*64 + ((lg*8)      ^ fk)];
                const short8 kf1 = *(const short8*)&K_lds[cur][kr*64 + ((32 + lg*8) ^ fk)];
                sa[n] = (floatx4){0.f, 0.f, 0.f, 0.f};
                sa[n] = __builtin_amdgcn_mfma_f32_16x16x32_bf16(kf0, qf[0], sa[n], 0, 0, 0);
                sa[n] = __builtin_amdgcn_mfma_f32_16x16x32_bf16(kf1, qf[1], sa[n], 0, 0, 0);
            }
            __builtin_amdgcn_s_setprio(0);

            if ((k0 + 64) > valid) {
                const int kb = k0 + lg*4;
#pragma unroll
                for (int n = 0; n < 4; ++n)
#pragma unroll
                for (int r = 0; r < 4; ++r)
                    sa[n][r] = (kb + n*16 + r >= valid) ? NEG_BIG : sa[n][r];
            }

            // ---- lane-local online softmax, deferred rescale ----
            float rmax = fmaxf(
                fmaxf(fmaxf(fmaxf(sa[0][0], sa[0][1]), fmaxf(sa[0][2], sa[0][3])),
                      fmaxf(fmaxf(sa[1][0], sa[1][1]), fmaxf(sa[1][2], sa[1][3]))),
                fmaxf(fmaxf(fmaxf(sa[2][0], sa[2][1]), fmaxf(sa[2][2], sa[2][3])),
                      fmaxf(fmaxf(sa[3][0], sa[3][1]), fmaxf(sa[3][2], sa[3][3]))));
            rmax = redmax16_32(rmax);

            if (!__all(rmax <= m + 11.0f)) {   // rescale (first tile + rare growth)
                const float nm = fmaxf(m, rmax);
                const float sc = EXP2F(m - nm);    // first tile: exp2(-inf)=0
                m = nm;
                lsum *= sc;
                float sc_r[4];
#pragma unroll
                for (int r = 0; r < 4; ++r) sc_r[r] = __shfl(sc, lg*4 + r);
#pragma unroll
                for (int n = 0; n < 4; ++n)
#pragma unroll
                for (int r = 0; r < 4; ++r) o[n][r] *= sc_r[r];
            }

            float rs = 0.f;
#pragma unroll
            for (int n = 0; n < 4; ++n)
#pragma unroll
            for (int r = 0; r < 4; ++r) {
                sa[n][r] = EXP2F(sa[n][r] - m);    // bounded by 2^11
                rs += sa[n][r];
            }
            lsum += redsum16_32(rs);

            // ---- P in-register -> A-fragments for 16x16x16 MFMA ----
            short4v pk[4];
#pragma unroll
            for (int n = 0; n < 4; ++n) {
                union { short4v s; __hip_bfloat162 h[2]; } u;
                u.h[0] = __float22bfloat162_rn(make_float2(sa[n][0], sa[n][1]));
                u.h[1] = __float22bfloat162_rn(make_float2(sa[n][2], sa[n][3]));
                pk[n] = u.s;
            }

            if (pf) WRITE_K(nxt);    // kra dies here

            // ---- PV: o[n2] += P[q][k] * V[k][dv] ----
            __builtin_amdgcn_s_setprio(1);
#pragma unroll
            for (int kc = 0; kc < 4; ++kc) {
#pragma unroll
                for (int n2 = 0; n2 < 4; ++n2) {
                    const int dv = n2*16 + lr;
                    const int fv = ((dv & 7) ^ (dv >> 3)) * 8;
                    const short4v vf = *(const short4v*)&VT_lds[cur][dv*64 + ((kc*16 + lg*4) ^ fv)];
                    o[n2] = MFMA16(pk[kc], vf, o[n2]);
                }
            }
            __builtin_amdgcn_s_setprio(0);

            if (pf) WRITE_V(nxt);    // vra dies here
            __syncthreads();         // one barrier per tile
        }

        // ---- epilogue: normalize and store (coalesced) ----
        {
            const float inv = 1.0f / lsum;
            float inv_r[4];
#pragma unroll
            for (int r = 0; r < 4; ++r) inv_r[r] = __shfl(inv, lg*4 + r);
            float* Ob = out + (size_t)b * 65536;
#pragma unroll
            for (int n = 0; n < 4; ++n)
#pragma unroll
            for (int r = 0; r < 4; ++r) {
                const int q = qc*64 + w*16 + lg*4 + r;
                Ob[(size_t)q * 64 + n*16 + lr] = o[n][r] * inv_r[r];
            }
        }
#undef LOAD_K
#undef LOAD_V
#undef WRITE_K
#undef WRITE_V
    }
}

extern "C" void kernel_launch(void* const* d_in, const int* in_sizes, int n_in,
                              void* d_out, int out_size, void* d_ws, size_t ws_size,
                              hipStream_t stream) {
    (void)in_sizes; (void)n_in; (void)out_size; (void)ws_size;
    const float* Q  = (const float*)d_in[0];
    const float* K  = (const float*)d_in[1];
    const float* V  = (const float*)d_in[2];
    const int*   vl = (const int*)d_in[3];
    float* O   = (float*)d_out;
    int*   ctr = (int*)d_ws;

    hipMemsetAsync(ctr, 0, sizeof(int), stream);   // graph-capturable
    attn_fwd<<<dim3(768), dim3(256), 0, stream>>>(Q, K, V, vl, O, ctr);
}

// Round 9
// 43.506 us; speedup vs baseline: 1.2449x; 1.2449x over previous
//
#include <hip/hip_runtime.h>
#include <hip/hip_bf16.h>

#define NEG_BIG -1000000.0f

typedef __attribute__((ext_vector_type(8))) short short8;
typedef __attribute__((ext_vector_type(4))) short short4v;
typedef __attribute__((ext_vector_type(4))) float floatx4;

#if __has_builtin(__builtin_amdgcn_exp2f)
#define EXP2F(x) __builtin_amdgcn_exp2f(x)
#else
#define EXP2F(x) exp2f(x)
#endif

// K=16 bf16 MFMA (PV step): A[row=lane&15][k=4*(lane>>4)+j]
#if __has_builtin(__builtin_amdgcn_mfma_f32_16x16x16bf16_1k)
#define MFMA16(a, b, c) __builtin_amdgcn_mfma_f32_16x16x16bf16_1k(a, b, c, 0, 0, 0)
#else
static __device__ __forceinline__ floatx4 MFMA16_fn(short4v a, short4v b, floatx4 c) {
    floatx4 d;
    asm("v_mfma_f32_16x16x16_bf16 %0, %1, %2, %3\n\ts_nop 4"
        : "=v"(d) : "v"(a), "v"(b), "v"(c));
    return d;
}
#define MFMA16(a, b, c) MFMA16_fn(a, b, c)
#endif

// xor16 + xor32 wave reduction on the VALU (permlane swaps) instead of
// ds_bpermute (LDS pipe, ~100cyc serial hops).
#if __has_builtin(__builtin_amdgcn_permlane16_swap) && __has_builtin(__builtin_amdgcn_permlane32_swap)
static __device__ __forceinline__ float redmax16_32(float x) {
    auto a = __builtin_amdgcn_permlane16_swap(__float_as_int(x), __float_as_int(x), false, false);
    x = fmaxf(__int_as_float(a[0]), __int_as_float(a[1]));
    auto b = __builtin_amdgcn_permlane32_swap(__float_as_int(x), __float_as_int(x), false, false);
    return fmaxf(__int_as_float(b[0]), __int_as_float(b[1]));
}
static __device__ __forceinline__ float redsum16_32(float x) {
    auto a = __builtin_amdgcn_permlane16_swap(__float_as_int(x), __float_as_int(x), false, false);
    x = __int_as_float(a[0]) + __int_as_float(a[1]);
    auto b = __builtin_amdgcn_permlane32_swap(__float_as_int(x), __float_as_int(x), false, false);
    return __int_as_float(b[0]) + __int_as_float(b[1]);
}
#else
static __device__ __forceinline__ float redmax16_32(float x) {
    x = fmaxf(x, __shfl_xor(x, 16));
    return fmaxf(x, __shfl_xor(x, 32));
}
static __device__ __forceinline__ float redsum16_32(float x) {
    x += __shfl_xor(x, 16);
    return x + __shfl_xor(x, 32);
}
#endif

static __device__ __forceinline__ unsigned short bf16u(float f) {
    union { __hip_bfloat16 h; unsigned short u; } c;
    c.h = __float2bfloat16(f);
    return c.u;
}

static __device__ __forceinline__ short8 pack8(float4 a, float4 b) {
    union { short8 s; __hip_bfloat162 h[4]; } u;
    u.h[0] = __float22bfloat162_rn(make_float2(a.x, a.y));
    u.h[1] = __float22bfloat162_rn(make_float2(a.z, a.w));
    u.h[2] = __float22bfloat162_rn(make_float2(b.x, b.y));
    u.h[3] = __float22bfloat162_rn(make_float2(b.z, b.w));
    return u.s;
}

// Block: 256 thr = 4 waves, 64 q-rows (wave owns one 16-row tile).
// Grid: 1024 blocks, XCD-swizzled, launch_bounds(256,4) -> 4 blocks/CU
// (LDS 4x32KB=128KB <= 160KB; body needs ~76 regs <= 128 cap, r8-measured)
// => ENTIRE grid co-resident from t=0: no queue, no drain phase; static
// mapping keeps each batch's 16 q-chunks on one XCD (L2-local K/V).
// KV tile 64, double-buffered 32 KB LDS, one barrier per tile, swapped QK^T
// (lane-local softmax, in-register P), permlane reductions, deferred
// rescale (THR=11, exp2 domain).
__global__ __launch_bounds__(256, 4)
void attn_fwd(const float* __restrict__ Q, const float* __restrict__ K,
              const float* __restrict__ V, const int* __restrict__ vlen,
              float* __restrict__ out)
{
    // K_lds: elem (row,col) at row*64 + (col ^ ((row&7)*8))
    __shared__ __attribute__((aligned(16))) unsigned short K_lds[2][4096];
    // VT_lds: elem (dv,k) at dv*64 + (k ^ (((dv&7) ^ (dv>>3)) * 8))
    __shared__ __attribute__((aligned(16))) unsigned short VT_lds[2][4096];

    const int bid  = blockIdx.x;
    const int orig = (bid & 7) * 128 + (bid >> 3);  // bijective (1024%8==0)
    const int b    = orig >> 4;
    const int qc   = orig & 15;

    const int tid = threadIdx.x;
    const int l   = tid & 63;
    const int w   = tid >> 6;
    const int lr  = l & 15;
    const int lg  = l >> 4;

    const float* Qb = Q + (size_t)b * 65536;
    const float* Kb = K + (size_t)b * 65536;
    const float* Vb = V + (size_t)b * 65536;

    const int valid = vlen[b];
    const int kmax  = (valid == 0) ? 1024 : valid;   // all-masked -> uniform
    const int ntile = (kmax + 63) >> 6;

    // Q fragments (B-operand of swapped QK^T), pre-scaled log2(e)/8
    const float qscale = 0.18033688011112042f;
    short8 qf[2];
#pragma unroll
    for (int c = 0; c < 2; ++c) {
        const float* p = Qb + (size_t)(qc*64 + w*16 + lr) * 64 + c*32 + lg*8;
        float4 a = *(const float4*)p, bb = *(const float4*)(p + 4);
        a.x *= qscale; a.y *= qscale; a.z *= qscale; a.w *= qscale;
        bb.x *= qscale; bb.y *= qscale; bb.z *= qscale; bb.w *= qscale;
        qf[c] = pack8(a, bb);
    }

    floatx4 o[4];
#pragma unroll
    for (int n = 0; n < 4; ++n) o[n] = (floatx4){0.f, 0.f, 0.f, 0.f};
    float m = -INFINITY, lsum = 0.f;      // scalar state for q-row lr

    // per-wave staging: wave w stages tile rows [w*16, w*16+16)
    const int row   = w * 16 + (l >> 2);  // 0..63
    const int cbase = (l & 3) * 16;       // col quarter (floats)

    float4 kra[4], vra[4];

#define LOAD_K(T) do {                                                      \
    const float* pk = Kb + (size_t)((T)*64 + row) * 64 + cbase;             \
    kra[0] = *(const float4*)pk;       kra[1] = *(const float4*)(pk + 4);   \
    kra[2] = *(const float4*)(pk + 8); kra[3] = *(const float4*)(pk + 12);  \
    } while (0)

#define LOAD_V(T) do {                                                      \
    const float* pv = Vb + (size_t)((T)*64 + row) * 64 + cbase;             \
    vra[0] = *(const float4*)pv;       vra[1] = *(const float4*)(pv + 4);   \
    vra[2] = *(const float4*)(pv + 8); vra[3] = *(const float4*)(pv + 12);  \
    } while (0)

#define WRITE_K(B) do {                                                     \
    const int _fk = (row & 7) * 8;                                          \
    *(short8*)&K_lds[B][row*64 + (cbase ^ _fk)]       = pack8(kra[0], kra[1]); \
    *(short8*)&K_lds[B][row*64 + ((cbase + 8) ^ _fk)] = pack8(kra[2], kra[3]); \
    } while (0)

#define WRITE_V(B) do {                                                     \
    _Pragma("unroll")                                                       \
    for (int j = 0; j < 16; ++j) {                                          \
        const int dv = cbase + j;                                           \
        const int fv = ((dv & 7) ^ (dv >> 3)) * 8;                          \
        VT_lds[B][dv*64 + (row ^ fv)] = bf16u(((const float*)&vra[j>>2])[j&3]); \
    } } while (0)

    LOAD_K(0);
    LOAD_V(0);
    WRITE_K(0);
    WRITE_V(0);
    __syncthreads();

    for (int t = 0; t < ntile; ++t) {
        const int cur = t & 1;
        const int nxt = cur ^ 1;
        const int k0  = t * 64;
        const bool pf = (t + 1 < ntile);

        if (pf) { LOAD_K(t + 1); LOAD_V(t + 1); }   // max load->use distance

        // ---- swapped QK^T: sa[n][r] = S[k=k0+n*16+lg*4+r][q=lr] ----
        floatx4 sa[4];
        __builtin_amdgcn_s_setprio(1);
#pragma unroll
        for (int n = 0; n < 4; ++n) {
            const int kr = n*16 + lr;
            const int fk = (lr & 7) * 8;
            const short8 kf0 = *(const short8*)&K_lds[cur][kr*64 + ((lg*8)      ^ fk)];
            const short8 kf1 = *(const short8*)&K_lds[cur][kr*64 + ((32 + lg*8) ^ fk)];
            sa[n] = (floatx4){0.f, 0.f, 0.f, 0.f};
            sa[n] = __builtin_amdgcn_mfma_f32_16x16x32_bf16(kf0, qf[0], sa[n], 0, 0, 0);
            sa[n] = __builtin_amdgcn_mfma_f32_16x16x32_bf16(kf1, qf[1], sa[n], 0, 0, 0);
        }
        __builtin_amdgcn_s_setprio(0);

        if ((k0 + 64) > valid) {
            const int kb = k0 + lg*4;
#pragma unroll
            for (int n = 0; n < 4; ++n)
#pragma unroll
            for (int r = 0; r < 4; ++r)
                sa[n][r] = (kb + n*16 + r >= valid) ? NEG_BIG : sa[n][r];
        }

        // ---- lane-local online softmax, deferred rescale ----
        float rmax = fmaxf(
            fmaxf(fmaxf(fmaxf(sa[0][0], sa[0][1]), fmaxf(sa[0][2], sa[0][3])),
                  fmaxf(fmaxf(sa[1][0], sa[1][1]), fmaxf(sa[1][2], sa[1][3]))),
            fmaxf(fmaxf(fmaxf(sa[2][0], sa[2][1]), fmaxf(sa[2][2], sa[2][3])),
                  fmaxf(fmaxf(sa[3][0], sa[3][1]), fmaxf(sa[3][2], sa[3][3]))));
        rmax = redmax16_32(rmax);

        if (!__all(rmax <= m + 11.0f)) {   // rescale (first tile + rare growth)
            const float nm = fmaxf(m, rmax);
            const float sc = EXP2F(m - nm);    // first tile: exp2(-inf)=0
            m = nm;
            lsum *= sc;
            float sc_r[4];
#pragma unroll
            for (int r = 0; r < 4; ++r) sc_r[r] = __shfl(sc, lg*4 + r);
#pragma unroll
            for (int n = 0; n < 4; ++n)
#pragma unroll
            for (int r = 0; r < 4; ++r) o[n][r] *= sc_r[r];
        }

        float rs = 0.f;
#pragma unroll
        for (int n = 0; n < 4; ++n)
#pragma unroll
        for (int r = 0; r < 4; ++r) {
            sa[n][r] = EXP2F(sa[n][r] - m);    // bounded by 2^11
            rs += sa[n][r];
        }
        lsum += redsum16_32(rs);

        // ---- P in-register -> A-fragments for 16x16x16 MFMA ----
        short4v pk[4];
#pragma unroll
        for (int n = 0; n < 4; ++n) {
            union { short4v s; __hip_bfloat162 h[2]; } u;
            u.h[0] = __float22bfloat162_rn(make_float2(sa[n][0], sa[n][1]));
            u.h[1] = __float22bfloat162_rn(make_float2(sa[n][2], sa[n][3]));
            pk[n] = u.s;
        }

        if (pf) WRITE_K(nxt);    // kra dies here

        // ---- PV: o[n2] += P[q][k] * V[k][dv] ----
        __builtin_amdgcn_s_setprio(1);
#pragma unroll
        for (int kc = 0; kc < 4; ++kc) {
#pragma unroll
            for (int n2 = 0; n2 < 4; ++n2) {
                const int dv = n2*16 + lr;
                const int fv = ((dv & 7) ^ (dv >> 3)) * 8;
                const short4v vf = *(const short4v*)&VT_lds[cur][dv*64 + ((kc*16 + lg*4) ^ fv)];
                o[n2] = MFMA16(pk[kc], vf, o[n2]);
            }
        }
        __builtin_amdgcn_s_setprio(0);

        if (pf) WRITE_V(nxt);    // vra dies here
        __syncthreads();         // one barrier per tile
    }

    // ---- epilogue: normalize and store (coalesced) ----
    const float inv = 1.0f / lsum;
    float inv_r[4];
#pragma unroll
    for (int r = 0; r < 4; ++r) inv_r[r] = __shfl(inv, lg*4 + r);

    float* Ob = out + (size_t)b * 65536;
#pragma unroll
    for (int n = 0; n < 4; ++n)
#pragma unroll
    for (int r = 0; r < 4; ++r) {
        const int q = qc*64 + w*16 + lg*4 + r;
        Ob[(size_t)q * 64 + n*16 + lr] = o[n][r] * inv_r[r];
    }
#undef LOAD_K
#undef LOAD_V
#undef WRITE_K
#undef WRITE_V
}

extern "C" void kernel_launch(void* const* d_in, const int* in_sizes, int n_in,
                              void* d_out, int out_size, void* d_ws, size_t ws_size,
                              hipStream_t stream) {
    (void)in_sizes; (void)n_in; (void)d_ws; (void)ws_size; (void)out_size;
    const float* Q  = (const float*)d_in[0];
    const float* K  = (const float*)d_in[1];
    const float* V  = (const float*)d_in[2];
    const int*   vl = (const int*)d_in[3];
    float* O = (float*)d_out;
    attn_fwd<<<dim3(1024), dim3(256), 0, stream>>>(Q, K, V, vl, O);
}